// Round 3
// baseline (920.224 us; speedup 1.0000x reference)
//
#include <hip/hip_runtime.h>
#include <hip/hip_bf16.h>

#define NN 8192
#define FIN 512
#define FOUT 256
#define JTILE 64
#define FDWIN 2048

typedef __attribute__((ext_vector_type(8))) short short8;
typedef __attribute__((ext_vector_type(4))) float float4v;
typedef __attribute__((ext_vector_type(4))) int int4v;
typedef __attribute__((ext_vector_type(16))) float float16v;

#if __has_builtin(__builtin_amdgcn_exp2f)
#define EXP2(x) __builtin_amdgcn_exp2f(x)
#else
#define EXP2(x) exp2f(x)
#endif

__device__ __forceinline__ short f2bf(float f) {
    union { float f; unsigned u; } v; v.f = f;
    unsigned r = (v.u + 0x7FFFu + ((v.u >> 16) & 1u)) >> 16;
    return (short)r;
}

// pack 2 f32 -> 2 bf16 (RNE), lo -> D[15:0], hi -> D[31:16]
__device__ __forceinline__ unsigned cvt_pk_bf16(float lo, float hi) {
    unsigned r;
    asm("v_cvt_pk_bf16_f32 %0, %1, %2" : "=v"(r) : "v"(lo), "v"(hi));
    return r;
}

// ---------------- Kernel 0: Wt[n][k] = bf16(W[k][n]), tiled transpose ----------------
__global__ __launch_bounds__(256) void wt_kernel(const float* __restrict__ W,
                                                 short* __restrict__ Wt) {
    __shared__ short tile[32][33];
    int tx = threadIdx.x & 31, ty = threadIdx.x >> 5;   // 32 x 8
    int k0 = blockIdx.x * 32, n0 = blockIdx.y * 32;
#pragma unroll
    for (int r = 0; r < 32; r += 8)
        tile[ty + r][tx] = f2bf(W[(size_t)(k0 + ty + r) * FOUT + n0 + tx]);
    __syncthreads();
#pragma unroll
    for (int r = 0; r < 32; r += 8)
        Wt[(size_t)(n0 + ty + r) * FIN + k0 + tx] = tile[tx][ty + r];
}

// ---------------- Kernel 1: h_t[n][m] = bf16((x@W)[m][n]); fused f_src/f_dst ----------------
__global__ __launch_bounds__(256) void h_kernel(const float* __restrict__ x,
                                                const short* __restrict__ Wt,
                                                const float* __restrict__ a,
                                                short* __restrict__ h_t,
                                                float* __restrict__ f_src,
                                                float* __restrict__ f_dst) {
    int wave = (blockIdx.x << 2) + (threadIdx.x >> 6);
    int lane = threadIdx.x & 63;
    int m0 = (wave & 511) << 4;
    int n0 = (wave >> 9) << 6;
    int lr = lane & 15, lq = lane >> 4;

    const float* xrow = x + (size_t)(m0 + lr) * FIN + lq * 8;
    const short* wbase = Wt + (size_t)(n0 + lr) * FIN + lq * 8;

    float4v acc[4] = {};
    for (int k0 = 0; k0 < FIN; k0 += 32) {
        float4v xa = *(const float4v*)(xrow + k0);
        float4v xb = *(const float4v*)(xrow + k0 + 4);
        short8 av;
        av[0] = f2bf(xa[0]); av[1] = f2bf(xa[1]); av[2] = f2bf(xa[2]); av[3] = f2bf(xa[3]);
        av[4] = f2bf(xb[0]); av[5] = f2bf(xb[1]); av[6] = f2bf(xb[2]); av[7] = f2bf(xb[3]);
#pragma unroll
        for (int ct = 0; ct < 4; ct++) {
            short8 bv = *(const short8*)(wbase + (size_t)ct * 16 * FIN + k0);
            acc[ct] = __builtin_amdgcn_mfma_f32_16x16x32_bf16(av, bv, acc[ct], 0, 0, 0);
        }
    }
    float s_part[4] = {0.f, 0.f, 0.f, 0.f};
    float d_part[4] = {0.f, 0.f, 0.f, 0.f};
#pragma unroll
    for (int ct = 0; ct < 4; ct++) {
        int n = n0 + ct * 16 + lr;
        float al = a[n], ar = a[FOUT + n];
#pragma unroll
        for (int reg = 0; reg < 4; reg++) {
            float hv = acc[ct][reg];
            s_part[reg] = fmaf(hv, al, s_part[reg]);
            d_part[reg] = fmaf(hv, ar, d_part[reg]);
            h_t[(size_t)n * NN + (m0 + lq * 4 + reg)] = f2bf(hv);
        }
    }
#pragma unroll
    for (int off = 1; off < 16; off <<= 1) {
#pragma unroll
        for (int reg = 0; reg < 4; reg++) {
            s_part[reg] += __shfl_xor(s_part[reg], off);
            d_part[reg] += __shfl_xor(d_part[reg], off);
        }
    }
    const float LOG2E = 1.4426950408889634f;
    if (lr == 0) {
#pragma unroll
        for (int reg = 0; reg < 4; reg++) {
            atomicAdd(&f_src[m0 + lq * 4 + reg], s_part[reg] * LOG2E);
            atomicAdd(&f_dst[m0 + lq * 4 + reg], d_part[reg] * LOG2E);
        }
    }
}

// ---------------- Kernel 2: fused masked-softmax-numerator @ h (j-sliced) ----------------
// v3: f_dst window staged ONCE in LDS (kills per-tile t<16 vmcnt-drain serializer);
// manual unroll-2 with disjoint E/O adj register sets (no copy-induced waits);
// issue order B-loads -> adj-prefetch so counted vmcnt never drains the adj stream
// (vmcnt retires in issue order!); non-temporal adj loads; 4 blocks/CU (grid==resident).
__global__ __launch_bounds__(256, 4) void gat_kernel(const int* __restrict__ adj,
                                                     const short* __restrict__ h_t,
                                                     const float* __restrict__ f_src,
                                                     const float* __restrict__ f_dst,
                                                     float* __restrict__ Opart,
                                                     float* __restrict__ lpart,
                                                     int jlen) {
    __shared__ short Pt[2][64 * 64];   // [row][j], XOR-swizzled (byte ^= (row&7)<<4), 2x8KB
    __shared__ float Fdall[FDWIN];     // whole f_dst window (<=8KB), staged once per window

    const int t = threadIdx.x;
    const int i0 = blockIdx.x * 64;
    const int slice = blockIdx.y;
    const int jbase = slice * jlen;

    const int prow = t >> 2, pjq = t & 3;            // P-compute role: 64 rows x 4 j-quads
    const int lane = t & 63, wv = t >> 6;
    const int l31 = lane & 31, lq = lane >> 5;
    const int wn0 = wv * 64;                         // wave's feature base

    const float fs = f_src[i0 + prow];
    const int* adjRow = adj + (size_t)(i0 + prow) * NN + jbase;
    const short* hb0 = h_t + (size_t)(wn0 + l31) * NN + jbase + lq * 8;
    const short* hb1 = hb0 + (size_t)32 * NN;

    float16v acc00 = {}, acc01 = {}, acc10 = {}, acc11 = {};
    float lp = 0.f;

    const int pswz = (prow & 7) << 4;
    const int rswz = (l31 & 7) << 4;
    const int wb = prow * 128 + pjq * 32;            // byte offset of this thread's P chunk
    const int ra = l31 * 128 + lq * 16;

    int4v avE0, avE1, avE2, avE3, avO0, avO1, avO2, avO3;

#define PEL(A, FI, I) { float y_ = fs + fdp[FI]; y_ = fmaxf(y_, 0.2f * y_); \
                        pv[I] = ((A) != 0) ? EXP2(y_) : 0.f; }

#define SUBTILE(BUF, R0, R1, R2, R3, W0, W1, W2, W3, JOB, JON)                          \
    {                                                                                   \
        short8 b0_[4], b1_[4];                                                          \
        _Pragma("unroll")                                                               \
        for (int kk = 0; kk < 4; kk++) {                                                \
            b0_[kk] = *(const short8*)(hb0 + (JOB) + kk * 16);                          \
            b1_[kk] = *(const short8*)(hb1 + (JOB) + kk * 16);                          \
        }                                                                               \
        {   /* adj prefetch: issued AFTER B so B's wait leaves it in flight */          \
            const int4v* ap_ = (const int4v*)(adjRow + (JON) + pjq * 16);               \
            W0 = __builtin_nontemporal_load(ap_);                                       \
            W1 = __builtin_nontemporal_load(ap_ + 1);                                   \
            W2 = __builtin_nontemporal_load(ap_ + 2);                                   \
            W3 = __builtin_nontemporal_load(ap_ + 3);                                   \
        }                                                                               \
        {                                                                               \
            const float* fdp = &Fdall[(JOB) - w0 + pjq * 16];                           \
            float pv[16];                                                               \
            PEL(R0[0], 0, 0)   PEL(R0[1], 1, 1)   PEL(R0[2], 2, 2)   PEL(R0[3], 3, 3)  \
            PEL(R1[0], 4, 4)   PEL(R1[1], 5, 5)   PEL(R1[2], 6, 6)   PEL(R1[3], 7, 7)  \
            PEL(R2[0], 8, 8)   PEL(R2[1], 9, 9)   PEL(R2[2], 10, 10) PEL(R2[3], 11, 11)\
            PEL(R3[0], 12, 12) PEL(R3[1], 13, 13) PEL(R3[2], 14, 14) PEL(R3[3], 15, 15)\
            lp += ((pv[0] + pv[1]) + (pv[2] + pv[3])) + ((pv[4] + pv[5]) + (pv[6] + pv[7])) \
                + ((pv[8] + pv[9]) + (pv[10] + pv[11])) + ((pv[12] + pv[13]) + (pv[14] + pv[15])); \
            int4v lov, hiv;                                                             \
            lov[0] = (int)cvt_pk_bf16(pv[0], pv[1]);                                    \
            lov[1] = (int)cvt_pk_bf16(pv[2], pv[3]);                                    \
            lov[2] = (int)cvt_pk_bf16(pv[4], pv[5]);                                    \
            lov[3] = (int)cvt_pk_bf16(pv[6], pv[7]);                                    \
            hiv[0] = (int)cvt_pk_bf16(pv[8], pv[9]);                                    \
            hiv[1] = (int)cvt_pk_bf16(pv[10], pv[11]);                                  \
            hiv[2] = (int)cvt_pk_bf16(pv[12], pv[13]);                                  \
            hiv[3] = (int)cvt_pk_bf16(pv[14], pv[15]);                                  \
            char* pbuf_ = (char*)&Pt[BUF][0];                                           \
            *(int4v*)(pbuf_ + (wb ^ pswz)) = lov;                                       \
            *(int4v*)(pbuf_ + ((wb + 16) ^ pswz)) = hiv;                                \
        }                                                                               \
        asm volatile("s_waitcnt lgkmcnt(0)\n\ts_barrier" ::: "memory");                 \
        __builtin_amdgcn_s_setprio(1);                                                  \
        {                                                                               \
            const char* pbuf_ = (const char*)&Pt[BUF][0];                               \
            _Pragma("unroll")                                                           \
            for (int kk = 0; kk < 4; kk++) {                                            \
                short8 a0_ = *(const short8*)(pbuf_ + ((ra + kk * 32) ^ rswz));         \
                short8 a1_ = *(const short8*)(pbuf_ + ((ra + 4096 + kk * 32) ^ rswz));  \
                acc00 = __builtin_amdgcn_mfma_f32_32x32x16_bf16(a0_, b0_[kk], acc00, 0, 0, 0); \
                acc01 = __builtin_amdgcn_mfma_f32_32x32x16_bf16(a0_, b1_[kk], acc01, 0, 0, 0); \
                acc10 = __builtin_amdgcn_mfma_f32_32x32x16_bf16(a1_, b0_[kk], acc10, 0, 0, 0); \
                acc11 = __builtin_amdgcn_mfma_f32_32x32x16_bf16(a1_, b1_[kk], acc11, 0, 0, 0); \
            }                                                                           \
        }                                                                               \
        __builtin_amdgcn_s_setprio(0);                                                  \
    }

    for (int w0 = 0; w0 < jlen; w0 += FDWIN) {
        const int wl = (jlen - w0 < FDWIN) ? (jlen - w0) : FDWIN;
        // stage f_dst window once (8 floats/thread)
        if (t * 8 < wl) {
            *(float4v*)&Fdall[t * 8]     = *(const float4v*)(f_dst + jbase + w0 + t * 8);
            *(float4v*)&Fdall[t * 8 + 4] = *(const float4v*)(f_dst + jbase + w0 + t * 8 + 4);
        }
        __syncthreads();
        // prologue adj prefetch for first E tile (issued after the full drain above)
        {
            const int4v* ap_ = (const int4v*)(adjRow + w0 + pjq * 16);
            avE0 = __builtin_nontemporal_load(ap_);
            avE1 = __builtin_nontemporal_load(ap_ + 1);
            avE2 = __builtin_nontemporal_load(ap_ + 2);
            avE3 = __builtin_nontemporal_load(ap_ + 3);
        }
        for (int jo = w0; jo < w0 + wl; jo += 2 * JTILE) {
            // E sub-tile: columns [jo, jo+64), buf 0, reads avE, prefetches avO
            SUBTILE(0, avE0, avE1, avE2, avE3, avO0, avO1, avO2, avO3,
                    jo, jo + JTILE)
            // O sub-tile: columns [jo+64, jo+128), buf 1, reads avO, prefetches avE
            const int jnn = (jo + 2 * JTILE < w0 + wl) ? (jo + 2 * JTILE) : w0;
            SUBTILE(1, avO0, avO1, avO2, avO3, avE0, avE1, avE2, avE3,
                    jo + JTILE, jnn)
        }
    }
#undef SUBTILE
#undef PEL

    // ---- epilogue: partial row-sum l, partial O ----
    lp += __shfl_xor(lp, 1);
    lp += __shfl_xor(lp, 2);
    if (pjq == 0) lpart[slice * NN + i0 + prow] = lp;

    float* obase = Opart + ((size_t)slice * NN + i0) * FOUT;
    // C/D 32x32: col = l31, row = (reg&3) + 8*(reg>>2) + 4*lq
#pragma unroll
    for (int rt = 0; rt < 2; rt++) {
#pragma unroll
        for (int nt = 0; nt < 2; nt++) {
            const float16v& av = rt == 0 ? (nt == 0 ? acc00 : acc01) : (nt == 0 ? acc10 : acc11);
#pragma unroll
            for (int reg = 0; reg < 16; reg++) {
                int row = rt * 32 + (reg & 3) + 8 * (reg >> 2) + 4 * lq;
                int n = wn0 + nt * 32 + l31;
                __builtin_nontemporal_store(av[reg], &obase[(size_t)row * FOUT + n]);
            }
        }
    }
}

// ---------------- Kernel 3: combine partials: out = sum_s O_s / sum_s l_s ----------------
__global__ __launch_bounds__(256) void combine_kernel(const float* __restrict__ Opart,
                                                      const float* __restrict__ lpart,
                                                      float* __restrict__ out, int slices) {
    int i = blockIdx.x, n = threadIdx.x;
    float o = 0.f, l = 0.f;
    for (int s = 0; s < slices; s++) {
        o += Opart[((size_t)s * NN + i) * FOUT + n];
        l += lpart[s * NN + i];
    }
    out[(size_t)i * FOUT + n] = o / l;
}

extern "C" void kernel_launch(void* const* d_in, const int* in_sizes, int n_in,
                              void* d_out, int out_size, void* d_ws, size_t ws_size,
                              hipStream_t stream) {
    const float* x   = (const float*)d_in[0];
    const int*   adj = (const int*)d_in[1];
    const float* W   = (const float*)d_in[2];
    const float* a   = (const float*)d_in[3];
    float* out = (float*)d_out;

    char* ws = (char*)d_ws;
    short* h_t   = (short*)ws;                                   // 4 MB
    short* Wt    = (short*)(ws + (4u << 20));                    // 256 KB
    float* f_src = (float*)(ws + (4u << 20) + (256u << 10));     // 32 KB
    float* f_dst = (float*)(ws + (4u << 20) + (288u << 10));     // 32 KB
    float* lpart = (float*)(ws + (4u << 20) + (320u << 10));     // up to 256 KB (8 slices)
    float* Opart = (float*)(ws + (5u << 20));                    // up to 64 MB

    const size_t OSLICE = (size_t)NN * FOUT * 4;                 // 8 MB per slice
    int slices = 1;
    if (ws_size >= (size_t)(5u << 20) + 8 * OSLICE) slices = 8;
    else if (ws_size >= (size_t)(5u << 20) + 4 * OSLICE) slices = 4;
    else if (ws_size >= (size_t)(5u << 20) + 2 * OSLICE) slices = 2;
    int jlen = NN / slices;

    hipMemsetAsync(f_src, 0, 2 * NN * sizeof(float), stream);
    wt_kernel<<<dim3(FIN / 32, FOUT / 32), 256, 0, stream>>>(W, Wt);
    h_kernel<<<512, 256, 0, stream>>>(x, Wt, a, h_t, f_src, f_dst);
    gat_kernel<<<dim3(NN / 64, slices), 256, 0, stream>>>(adj, h_t, f_src, f_dst,
                                                          Opart, lpart, jlen);
    combine_kernel<<<NN, 256, 0, stream>>>(Opart, lpart, out, slices);
}

// Round 4
// 621.117 us; speedup vs baseline: 1.4816x; 1.4816x over previous
//
#include <hip/hip_runtime.h>
#include <hip/hip_bf16.h>

#define NN 8192
#define FIN 512
#define FOUT 256
#define JTILE 64
#define FDWIN 2048

typedef __attribute__((ext_vector_type(8))) short short8;
typedef __attribute__((ext_vector_type(4))) float float4v;
typedef __attribute__((ext_vector_type(4))) int int4v;
typedef __attribute__((ext_vector_type(16))) float float16v;

#if __has_builtin(__builtin_amdgcn_exp2f)
#define EXP2(x) __builtin_amdgcn_exp2f(x)
#else
#define EXP2(x) exp2f(x)
#endif

__device__ __forceinline__ short f2bf(float f) {
    union { float f; unsigned u; } v; v.f = f;
    unsigned r = (v.u + 0x7FFFu + ((v.u >> 16) & 1u)) >> 16;
    return (short)r;
}

// pack 2 f32 -> 2 bf16 (RNE), lo -> D[15:0], hi -> D[31:16]
__device__ __forceinline__ unsigned cvt_pk_bf16(float lo, float hi) {
    unsigned r;
    asm("v_cvt_pk_bf16_f32 %0, %1, %2" : "=v"(r) : "v"(lo), "v"(hi));
    return r;
}

// ---------------- Kernel 0: Wt[n][k] = bf16(W[k][n]), tiled transpose ----------------
__global__ __launch_bounds__(256) void wt_kernel(const float* __restrict__ W,
                                                 short* __restrict__ Wt) {
    __shared__ short tile[32][33];
    int tx = threadIdx.x & 31, ty = threadIdx.x >> 5;   // 32 x 8
    int k0 = blockIdx.x * 32, n0 = blockIdx.y * 32;
#pragma unroll
    for (int r = 0; r < 32; r += 8)
        tile[ty + r][tx] = f2bf(W[(size_t)(k0 + ty + r) * FOUT + n0 + tx]);
    __syncthreads();
#pragma unroll
    for (int r = 0; r < 32; r += 8)
        Wt[(size_t)(n0 + ty + r) * FIN + k0 + tx] = tile[tx][ty + r];
}

// ---------------- Kernel 1: h_t[n][m] = bf16((x@W)[m][n]); fused f_src/f_dst ----------------
__global__ __launch_bounds__(256) void h_kernel(const float* __restrict__ x,
                                                const short* __restrict__ Wt,
                                                const float* __restrict__ a,
                                                short* __restrict__ h_t,
                                                float* __restrict__ f_src,
                                                float* __restrict__ f_dst) {
    int wave = (blockIdx.x << 2) + (threadIdx.x >> 6);
    int lane = threadIdx.x & 63;
    int m0 = (wave & 511) << 4;
    int n0 = (wave >> 9) << 6;
    int lr = lane & 15, lq = lane >> 4;

    const float* xrow = x + (size_t)(m0 + lr) * FIN + lq * 8;
    const short* wbase = Wt + (size_t)(n0 + lr) * FIN + lq * 8;

    float4v acc[4] = {};
    for (int k0 = 0; k0 < FIN; k0 += 32) {
        float4v xa = *(const float4v*)(xrow + k0);
        float4v xb = *(const float4v*)(xrow + k0 + 4);
        short8 av;
        av[0] = f2bf(xa[0]); av[1] = f2bf(xa[1]); av[2] = f2bf(xa[2]); av[3] = f2bf(xa[3]);
        av[4] = f2bf(xb[0]); av[5] = f2bf(xb[1]); av[6] = f2bf(xb[2]); av[7] = f2bf(xb[3]);
#pragma unroll
        for (int ct = 0; ct < 4; ct++) {
            short8 bv = *(const short8*)(wbase + (size_t)ct * 16 * FIN + k0);
            acc[ct] = __builtin_amdgcn_mfma_f32_16x16x32_bf16(av, bv, acc[ct], 0, 0, 0);
        }
    }
    float s_part[4] = {0.f, 0.f, 0.f, 0.f};
    float d_part[4] = {0.f, 0.f, 0.f, 0.f};
#pragma unroll
    for (int ct = 0; ct < 4; ct++) {
        int n = n0 + ct * 16 + lr;
        float al = a[n], ar = a[FOUT + n];
#pragma unroll
        for (int reg = 0; reg < 4; reg++) {
            float hv = acc[ct][reg];
            s_part[reg] = fmaf(hv, al, s_part[reg]);
            d_part[reg] = fmaf(hv, ar, d_part[reg]);
            h_t[(size_t)n * NN + (m0 + lq * 4 + reg)] = f2bf(hv);
        }
    }
#pragma unroll
    for (int off = 1; off < 16; off <<= 1) {
#pragma unroll
        for (int reg = 0; reg < 4; reg++) {
            s_part[reg] += __shfl_xor(s_part[reg], off);
            d_part[reg] += __shfl_xor(d_part[reg], off);
        }
    }
    const float LOG2E = 1.4426950408889634f;
    if (lr == 0) {
#pragma unroll
        for (int reg = 0; reg < 4; reg++) {
            atomicAdd(&f_src[m0 + lq * 4 + reg], s_part[reg] * LOG2E);
            atomicAdd(&f_dst[m0 + lq * 4 + reg], d_part[reg] * LOG2E);
        }
    }
}

// ---------------- Kernel 2: fused masked-softmax-numerator @ h (j-sliced) ----------------
// v4: launch_bounds(256,3) -> 170 unified regs/wave (v3's (256,4)=128 cap spilled ~1.9GB
// to scratch: VGPR=64 + FETCH/WRITE ~1GB each). Grid = 128 x 6 slices = 768 blocks =
// exactly 3 blocks/CU x 256 CU (zero straggler round). Slice lengths are uneven
// multiples of 128 cols, computed from (q,r) tiles-of-128.
__global__ __launch_bounds__(256, 3) void gat_kernel(const int* __restrict__ adj,
                                                     const short* __restrict__ h_t,
                                                     const float* __restrict__ f_src,
                                                     const float* __restrict__ f_dst,
                                                     float* __restrict__ Opart,
                                                     float* __restrict__ lpart,
                                                     int qt, int rt_) {
    __shared__ short Pt[2][64 * 64];   // [row][j], XOR-swizzled (byte ^= (row&7)<<4), 2x8KB
    __shared__ float Fdall[FDWIN];     // f_dst window (<=8KB), staged once per window

    const int t = threadIdx.x;
    const int i0 = blockIdx.x * 64;
    const int slice = blockIdx.y;
    // slice s covers tiles [s*qt + min(s,rt_), +qt + (s<rt_)) of 128 columns each
    const int stile = slice * qt + (slice < rt_ ? slice : rt_);
    const int jbase = stile * 128;
    const int jlen = (qt + (slice < rt_ ? 1 : 0)) * 128;

    const int prow = t >> 2, pjq = t & 3;            // P-compute role: 64 rows x 4 j-quads
    const int lane = t & 63, wv = t >> 6;
    const int l31 = lane & 31, lq = lane >> 5;
    const int wn0 = wv * 64;                         // wave's feature base

    const float fs = f_src[i0 + prow];
    const int* adjRow = adj + (size_t)(i0 + prow) * NN + jbase;
    const short* hb0 = h_t + (size_t)(wn0 + l31) * NN + jbase + lq * 8;
    const short* hb1 = hb0 + (size_t)32 * NN;

    float16v acc00 = {}, acc01 = {}, acc10 = {}, acc11 = {};
    float lp = 0.f;

    const int pswz = (prow & 7) << 4;
    const int rswz = (l31 & 7) << 4;
    const int wb = prow * 128 + pjq * 32;            // byte offset of this thread's P chunk
    const int ra = l31 * 128 + lq * 16;

    int4v avE0, avE1, avE2, avE3, avO0, avO1, avO2, avO3;

#define PEL(A, FI, I) { float y_ = fs + fdp[FI]; y_ = fmaxf(y_, 0.2f * y_); \
                        pv[I] = ((A) != 0) ? EXP2(y_) : 0.f; }

#define SUBTILE(BUF, R0, R1, R2, R3, W0, W1, W2, W3, JOB, JON)                          \
    {                                                                                   \
        short8 b0_[4], b1_[4];                                                          \
        _Pragma("unroll")                                                               \
        for (int kk = 0; kk < 4; kk++) {                                                \
            b0_[kk] = *(const short8*)(hb0 + (JOB) + kk * 16);                          \
            b1_[kk] = *(const short8*)(hb1 + (JOB) + kk * 16);                          \
        }                                                                               \
        {   /* adj prefetch: issued AFTER B so B's wait leaves it in flight */          \
            const int4v* ap_ = (const int4v*)(adjRow + (JON) + pjq * 16);               \
            W0 = __builtin_nontemporal_load(ap_);                                       \
            W1 = __builtin_nontemporal_load(ap_ + 1);                                   \
            W2 = __builtin_nontemporal_load(ap_ + 2);                                   \
            W3 = __builtin_nontemporal_load(ap_ + 3);                                   \
        }                                                                               \
        {                                                                               \
            const float* fdp = &Fdall[(JOB) - w0 + pjq * 16];                           \
            float pv[16];                                                               \
            PEL(R0[0], 0, 0)   PEL(R0[1], 1, 1)   PEL(R0[2], 2, 2)   PEL(R0[3], 3, 3)  \
            PEL(R1[0], 4, 4)   PEL(R1[1], 5, 5)   PEL(R1[2], 6, 6)   PEL(R1[3], 7, 7)  \
            PEL(R2[0], 8, 8)   PEL(R2[1], 9, 9)   PEL(R2[2], 10, 10) PEL(R2[3], 11, 11)\
            PEL(R3[0], 12, 12) PEL(R3[1], 13, 13) PEL(R3[2], 14, 14) PEL(R3[3], 15, 15)\
            lp += ((pv[0] + pv[1]) + (pv[2] + pv[3])) + ((pv[4] + pv[5]) + (pv[6] + pv[7])) \
                + ((pv[8] + pv[9]) + (pv[10] + pv[11])) + ((pv[12] + pv[13]) + (pv[14] + pv[15])); \
            int4v lov, hiv;                                                             \
            lov[0] = (int)cvt_pk_bf16(pv[0], pv[1]);                                    \
            lov[1] = (int)cvt_pk_bf16(pv[2], pv[3]);                                    \
            lov[2] = (int)cvt_pk_bf16(pv[4], pv[5]);                                    \
            lov[3] = (int)cvt_pk_bf16(pv[6], pv[7]);                                    \
            hiv[0] = (int)cvt_pk_bf16(pv[8], pv[9]);                                    \
            hiv[1] = (int)cvt_pk_bf16(pv[10], pv[11]);                                  \
            hiv[2] = (int)cvt_pk_bf16(pv[12], pv[13]);                                  \
            hiv[3] = (int)cvt_pk_bf16(pv[14], pv[15]);                                  \
            char* pbuf_ = (char*)&Pt[BUF][0];                                           \
            *(int4v*)(pbuf_ + (wb ^ pswz)) = lov;                                       \
            *(int4v*)(pbuf_ + ((wb + 16) ^ pswz)) = hiv;                                \
        }                                                                               \
        asm volatile("s_waitcnt lgkmcnt(0)\n\ts_barrier" ::: "memory");                 \
        __builtin_amdgcn_s_setprio(1);                                                  \
        {                                                                               \
            const char* pbuf_ = (const char*)&Pt[BUF][0];                               \
            _Pragma("unroll")                                                           \
            for (int kk = 0; kk < 4; kk++) {                                            \
                short8 a0_ = *(const short8*)(pbuf_ + ((ra + kk * 32) ^ rswz));         \
                short8 a1_ = *(const short8*)(pbuf_ + ((ra + 4096 + kk * 32) ^ rswz));  \
                acc00 = __builtin_amdgcn_mfma_f32_32x32x16_bf16(a0_, b0_[kk], acc00, 0, 0, 0); \
                acc01 = __builtin_amdgcn_mfma_f32_32x32x16_bf16(a0_, b1_[kk], acc01, 0, 0, 0); \
                acc10 = __builtin_amdgcn_mfma_f32_32x32x16_bf16(a1_, b0_[kk], acc10, 0, 0, 0); \
                acc11 = __builtin_amdgcn_mfma_f32_32x32x16_bf16(a1_, b1_[kk], acc11, 0, 0, 0); \
            }                                                                           \
        }                                                                               \
        __builtin_amdgcn_s_setprio(0);                                                  \
    }

    for (int w0 = 0; w0 < jlen; w0 += FDWIN) {
        const int wl = (jlen - w0 < FDWIN) ? (jlen - w0) : FDWIN;
        // stage f_dst window once (8 floats/thread)
        if (t * 8 < wl) {
            *(float4v*)&Fdall[t * 8]     = *(const float4v*)(f_dst + jbase + w0 + t * 8);
            *(float4v*)&Fdall[t * 8 + 4] = *(const float4v*)(f_dst + jbase + w0 + t * 8 + 4);
        }
        __syncthreads();
        // prologue adj prefetch for first E tile (issued after the full drain above)
        {
            const int4v* ap_ = (const int4v*)(adjRow + w0 + pjq * 16);
            avE0 = __builtin_nontemporal_load(ap_);
            avE1 = __builtin_nontemporal_load(ap_ + 1);
            avE2 = __builtin_nontemporal_load(ap_ + 2);
            avE3 = __builtin_nontemporal_load(ap_ + 3);
        }
        for (int jo = w0; jo < w0 + wl; jo += 2 * JTILE) {
            // E sub-tile: columns [jo, jo+64), buf 0, reads avE, prefetches avO
            SUBTILE(0, avE0, avE1, avE2, avE3, avO0, avO1, avO2, avO3,
                    jo, jo + JTILE)
            // O sub-tile: columns [jo+64, jo+128), buf 1, reads avO, prefetches avE
            const int jnn = (jo + 2 * JTILE < w0 + wl) ? (jo + 2 * JTILE) : w0;
            SUBTILE(1, avO0, avO1, avO2, avO3, avE0, avE1, avE2, avE3,
                    jo + JTILE, jnn)
        }
    }
#undef SUBTILE
#undef PEL

    // ---- epilogue: partial row-sum l, partial O ----
    lp += __shfl_xor(lp, 1);
    lp += __shfl_xor(lp, 2);
    if (pjq == 0) lpart[slice * NN + i0 + prow] = lp;

    float* obase = Opart + ((size_t)slice * NN + i0) * FOUT;
    // C/D 32x32: col = l31, row = (reg&3) + 8*(reg>>2) + 4*lq
#pragma unroll
    for (int rt = 0; rt < 2; rt++) {
#pragma unroll
        for (int nt = 0; nt < 2; nt++) {
            const float16v& av = rt == 0 ? (nt == 0 ? acc00 : acc01) : (nt == 0 ? acc10 : acc11);
#pragma unroll
            for (int reg = 0; reg < 16; reg++) {
                int row = rt * 32 + (reg & 3) + 8 * (reg >> 2) + 4 * lq;
                int n = wn0 + nt * 32 + l31;
                obase[(size_t)row * FOUT + n] = av[reg];
            }
        }
    }
}

// ---------------- Kernel 3: combine partials: out = sum_s O_s / sum_s l_s ----------------
__global__ __launch_bounds__(256) void combine_kernel(const float* __restrict__ Opart,
                                                      const float* __restrict__ lpart,
                                                      float* __restrict__ out, int slices) {
    int i = blockIdx.x, n = threadIdx.x;
    float o = 0.f, l = 0.f;
    for (int s = 0; s < slices; s++) {
        o += Opart[((size_t)s * NN + i) * FOUT + n];
        l += lpart[s * NN + i];
    }
    out[(size_t)i * FOUT + n] = o / l;
}

extern "C" void kernel_launch(void* const* d_in, const int* in_sizes, int n_in,
                              void* d_out, int out_size, void* d_ws, size_t ws_size,
                              hipStream_t stream) {
    const float* x   = (const float*)d_in[0];
    const int*   adj = (const int*)d_in[1];
    const float* W   = (const float*)d_in[2];
    const float* a   = (const float*)d_in[3];
    float* out = (float*)d_out;

    char* ws = (char*)d_ws;
    short* h_t   = (short*)ws;                                   // 4 MB
    short* Wt    = (short*)(ws + (4u << 20));                    // 256 KB
    float* f_src = (float*)(ws + (4u << 20) + (256u << 10));     // 32 KB
    float* f_dst = (float*)(ws + (4u << 20) + (288u << 10));     // 32 KB
    float* lpart = (float*)(ws + (4u << 20) + (320u << 10));     // up to 256 KB (8 slices)
    float* Opart = (float*)(ws + (5u << 20));                    // up to 64 MB

    const size_t OSLICE = (size_t)NN * FOUT * 4;                 // 8 MB per slice
    int slices = 1;
    if (ws_size >= (size_t)(5u << 20) + 6 * OSLICE) slices = 6;  // grid 768 = 3/CU exact
    else if (ws_size >= (size_t)(5u << 20) + 4 * OSLICE) slices = 4;
    else if (ws_size >= (size_t)(5u << 20) + 2 * OSLICE) slices = 2;
    const int NTILES = NN / 128;                                 // 64 tiles of 128 cols
    int qt = NTILES / slices, rt_ = NTILES % slices;

    hipMemsetAsync(f_src, 0, 2 * NN * sizeof(float), stream);
    wt_kernel<<<dim3(FIN / 32, FOUT / 32), 256, 0, stream>>>(W, Wt);
    h_kernel<<<512, 256, 0, stream>>>(x, Wt, a, h_t, f_src, f_dst);
    gat_kernel<<<dim3(NN / 64, slices), 256, 0, stream>>>(adj, h_t, f_src, f_dst,
                                                          Opart, lpart, qt, rt_);
    combine_kernel<<<NN, 256, 0, stream>>>(Opart, lpart, out, slices);
}

// Round 5
// 476.251 us; speedup vs baseline: 1.9322x; 1.3042x over previous
//
#include <hip/hip_runtime.h>
#include <hip/hip_bf16.h>

#define NN 8192
#define FIN 512
#define FOUT 256
#define JTILE 64
#define FDWIN 2048

typedef __attribute__((ext_vector_type(8))) short short8;
typedef __attribute__((ext_vector_type(4))) float float4v;
typedef __attribute__((ext_vector_type(4))) int int4v;
typedef __attribute__((ext_vector_type(16))) float float16v;

#if __has_builtin(__builtin_amdgcn_exp2f)
#define EXP2(x) __builtin_amdgcn_exp2f(x)
#else
#define EXP2(x) exp2f(x)
#endif

__device__ __forceinline__ short f2bf(float f) {
    union { float f; unsigned u; } v; v.f = f;
    unsigned r = (v.u + 0x7FFFu + ((v.u >> 16) & 1u)) >> 16;
    return (short)r;
}

// pack 2 f32 -> 2 bf16 (RNE), lo -> D[15:0], hi -> D[31:16]
__device__ __forceinline__ unsigned cvt_pk_bf16(float lo, float hi) {
    unsigned r;
    asm("v_cvt_pk_bf16_f32 %0, %1, %2" : "=v"(r) : "v"(lo), "v"(hi));
    return r;
}

// ---------------- Kernel 0: Wt[n][k] = bf16(W[k][n]), tiled transpose ----------------
__global__ __launch_bounds__(256) void wt_kernel(const float* __restrict__ W,
                                                 short* __restrict__ Wt) {
    __shared__ short tile[32][33];
    int tx = threadIdx.x & 31, ty = threadIdx.x >> 5;   // 32 x 8
    int k0 = blockIdx.x * 32, n0 = blockIdx.y * 32;
#pragma unroll
    for (int r = 0; r < 32; r += 8)
        tile[ty + r][tx] = f2bf(W[(size_t)(k0 + ty + r) * FOUT + n0 + tx]);
    __syncthreads();
#pragma unroll
    for (int r = 0; r < 32; r += 8)
        Wt[(size_t)(n0 + ty + r) * FIN + k0 + tx] = tile[tx][ty + r];
}

// ---------------- Kernel 1: h_t[n][m] = bf16((x@W)[m][n]); fused f_src/f_dst ----------------
__global__ __launch_bounds__(256) void h_kernel(const float* __restrict__ x,
                                                const short* __restrict__ Wt,
                                                const float* __restrict__ a,
                                                short* __restrict__ h_t,
                                                float* __restrict__ f_src,
                                                float* __restrict__ f_dst) {
    int wave = (blockIdx.x << 2) + (threadIdx.x >> 6);
    int lane = threadIdx.x & 63;
    int m0 = (wave & 511) << 4;
    int n0 = (wave >> 9) << 6;
    int lr = lane & 15, lq = lane >> 4;

    const float* xrow = x + (size_t)(m0 + lr) * FIN + lq * 8;
    const short* wbase = Wt + (size_t)(n0 + lr) * FIN + lq * 8;

    float4v acc[4] = {};
    for (int k0 = 0; k0 < FIN; k0 += 32) {
        float4v xa = *(const float4v*)(xrow + k0);
        float4v xb = *(const float4v*)(xrow + k0 + 4);
        short8 av;
        av[0] = f2bf(xa[0]); av[1] = f2bf(xa[1]); av[2] = f2bf(xa[2]); av[3] = f2bf(xa[3]);
        av[4] = f2bf(xb[0]); av[5] = f2bf(xb[1]); av[6] = f2bf(xb[2]); av[7] = f2bf(xb[3]);
#pragma unroll
        for (int ct = 0; ct < 4; ct++) {
            short8 bv = *(const short8*)(wbase + (size_t)ct * 16 * FIN + k0);
            acc[ct] = __builtin_amdgcn_mfma_f32_16x16x32_bf16(av, bv, acc[ct], 0, 0, 0);
        }
    }
    float s_part[4] = {0.f, 0.f, 0.f, 0.f};
    float d_part[4] = {0.f, 0.f, 0.f, 0.f};
#pragma unroll
    for (int ct = 0; ct < 4; ct++) {
        int n = n0 + ct * 16 + lr;
        float al = a[n], ar = a[FOUT + n];
#pragma unroll
        for (int reg = 0; reg < 4; reg++) {
            float hv = acc[ct][reg];
            s_part[reg] = fmaf(hv, al, s_part[reg]);
            d_part[reg] = fmaf(hv, ar, d_part[reg]);
            h_t[(size_t)n * NN + (m0 + lq * 4 + reg)] = f2bf(hv);
        }
    }
#pragma unroll
    for (int off = 1; off < 16; off <<= 1) {
#pragma unroll
        for (int reg = 0; reg < 4; reg++) {
            s_part[reg] += __shfl_xor(s_part[reg], off);
            d_part[reg] += __shfl_xor(d_part[reg], off);
        }
    }
    const float LOG2E = 1.4426950408889634f;
    if (lr == 0) {
#pragma unroll
        for (int reg = 0; reg < 4; reg++) {
            atomicAdd(&f_src[m0 + lq * 4 + reg], s_part[reg] * LOG2E);
            atomicAdd(&f_dst[m0 + lq * 4 + reg], d_part[reg] * LOG2E);
        }
    }
}

// ---------------- Kernel 2: fused masked-softmax-numerator @ h (j-sliced) ----------------
// v5: register-pressure fix. v4 spilled (~400MB scratch WRITE): acc64 + B32 + E/O adj 32
// + pv16 + misc ~= 170-cap. Now: SINGLE adj reg buffer (next tile loaded into same regs
// right after last use -- no copies), pv[16] folded into pairwise cvt_pk (pk[8]).
// Peak ~140 regs < 170 @ 3 waves/SIMD. Issue order kept: B-loads FIRST, adj-next after
// P-compute, so vmcnt waits on B (older) never drain the adj prefetch (younger).
__global__ __launch_bounds__(256, 3) void gat_kernel(const int* __restrict__ adj,
                                                     const short* __restrict__ h_t,
                                                     const float* __restrict__ f_src,
                                                     const float* __restrict__ f_dst,
                                                     float* __restrict__ Opart,
                                                     float* __restrict__ lpart,
                                                     int qt, int rt_) {
    __shared__ short Pt[2][64 * 64];   // [row][j], XOR-swizzled (byte ^= (row&7)<<4), 2x8KB
    __shared__ float Fdall[FDWIN];     // f_dst window (<=8KB), staged once per window

    const int t = threadIdx.x;
    const int i0 = blockIdx.x * 64;
    const int slice = blockIdx.y;
    // slice s covers tiles [s*qt + min(s,rt_), +qt + (s<rt_)) of 128 columns each
    const int stile = slice * qt + (slice < rt_ ? slice : rt_);
    const int jbase = stile * 128;
    const int jlen = (qt + (slice < rt_ ? 1 : 0)) * 128;

    const int prow = t >> 2, pjq = t & 3;            // P-compute role: 64 rows x 4 j-quads
    const int lane = t & 63, wv = t >> 6;
    const int l31 = lane & 31, lq = lane >> 5;
    const int wn0 = wv * 64;                         // wave's feature base

    const float fs = f_src[i0 + prow];
    const int* adjRow = adj + (size_t)(i0 + prow) * NN + jbase;
    const short* hb0 = h_t + (size_t)(wn0 + l31) * NN + jbase + lq * 8;
    const short* hb1 = hb0 + (size_t)32 * NN;

    float16v acc00 = {}, acc01 = {}, acc10 = {}, acc11 = {};
    float lp = 0.f;

    const int pswz = (prow & 7) << 4;
    const int rswz = (l31 & 7) << 4;
    const int wb = prow * 128 + pjq * 32;            // byte offset of this thread's P chunk
    const int ra = l31 * 128 + lq * 16;

    int4v av0, av1, av2, av3;                        // single adj buffer (current tile)

#define PPAIR(AE0, AE1, FI, PKI)                                        \
    {                                                                   \
        float y0 = fs + fdp[FI], y1 = fs + fdp[(FI) + 1];               \
        y0 = fmaxf(y0, 0.2f * y0); y1 = fmaxf(y1, 0.2f * y1);           \
        float p0 = ((AE0) != 0) ? EXP2(y0) : 0.f;                       \
        float p1 = ((AE1) != 0) ? EXP2(y1) : 0.f;                       \
        lp += p0 + p1;                                                  \
        pk[PKI] = cvt_pk_bf16(p0, p1);                                  \
    }

    for (int w0 = 0; w0 < jlen; w0 += FDWIN) {
        const int wl = (jlen - w0 < FDWIN) ? (jlen - w0) : FDWIN;
        // stage f_dst window once (8 floats/thread)
        if (t * 8 < wl) {
            *(float4v*)&Fdall[t * 8]     = *(const float4v*)(f_dst + jbase + w0 + t * 8);
            *(float4v*)&Fdall[t * 8 + 4] = *(const float4v*)(f_dst + jbase + w0 + t * 8 + 4);
        }
        __syncthreads();
        // prologue: adj load for first tile (only full-latency wait per window)
        {
            const int4v* ap_ = (const int4v*)(adjRow + w0 + pjq * 16);
            av0 = __builtin_nontemporal_load(ap_);
            av1 = __builtin_nontemporal_load(ap_ + 1);
            av2 = __builtin_nontemporal_load(ap_ + 2);
            av3 = __builtin_nontemporal_load(ap_ + 3);
        }
        for (int jo = w0; jo < w0 + wl; jo += JTILE) {
            const int buf = (jo >> 6) & 1;
            // 1. B preload for THIS tile -- issued first; L2 latency hides under P compute
            short8 b0_[4], b1_[4];
#pragma unroll
            for (int kk = 0; kk < 4; kk++) {
                b0_[kk] = *(const short8*)(hb0 + jo + kk * 16);
                b1_[kk] = *(const short8*)(hb1 + jo + kk * 16);
            }
            // 2. P compute from av (consumes adj of this tile), pairwise pack
            {
                const float* fdp = &Fdall[jo - w0 + pjq * 16];
                unsigned pk[8];
                PPAIR(av0[0], av0[1], 0, 0)  PPAIR(av0[2], av0[3], 2, 1)
                PPAIR(av1[0], av1[1], 4, 2)  PPAIR(av1[2], av1[3], 6, 3)
                PPAIR(av2[0], av2[1], 8, 4)  PPAIR(av2[2], av2[3], 10, 5)
                PPAIR(av3[0], av3[1], 12, 6) PPAIR(av3[2], av3[3], 14, 7)
                char* pbuf_ = (char*)&Pt[buf][0];
                int4v lov, hiv;
                lov[0] = (int)pk[0]; lov[1] = (int)pk[1]; lov[2] = (int)pk[2]; lov[3] = (int)pk[3];
                hiv[0] = (int)pk[4]; hiv[1] = (int)pk[5]; hiv[2] = (int)pk[6]; hiv[3] = (int)pk[7];
                *(int4v*)(pbuf_ + (wb ^ pswz)) = lov;
                *(int4v*)(pbuf_ + ((wb + 16) ^ pswz)) = hiv;
            }
            // 3. adj prefetch for NEXT tile into the SAME regs (after last use, no copies);
            //    issued after B so B's vmcnt wait leaves these in flight through MFMA
            {
                const int jn = (jo + JTILE < w0 + wl) ? (jo + JTILE) : w0;
                const int4v* ap_ = (const int4v*)(adjRow + jn + pjq * 16);
                av0 = __builtin_nontemporal_load(ap_);
                av1 = __builtin_nontemporal_load(ap_ + 1);
                av2 = __builtin_nontemporal_load(ap_ + 2);
                av3 = __builtin_nontemporal_load(ap_ + 3);
            }
            // 4. barrier: drain LDS only, keep global prefetches in flight
            asm volatile("s_waitcnt lgkmcnt(0)\n\ts_barrier" ::: "memory");
            // 5. MFMA phase
            __builtin_amdgcn_s_setprio(1);
            {
                const char* pbuf_ = (const char*)&Pt[buf][0];
#pragma unroll
                for (int kk = 0; kk < 4; kk++) {
                    short8 a0_ = *(const short8*)(pbuf_ + ((ra + kk * 32) ^ rswz));
                    short8 a1_ = *(const short8*)(pbuf_ + ((ra + 4096 + kk * 32) ^ rswz));
                    acc00 = __builtin_amdgcn_mfma_f32_32x32x16_bf16(a0_, b0_[kk], acc00, 0, 0, 0);
                    acc01 = __builtin_amdgcn_mfma_f32_32x32x16_bf16(a0_, b1_[kk], acc01, 0, 0, 0);
                    acc10 = __builtin_amdgcn_mfma_f32_32x32x16_bf16(a1_, b0_[kk], acc10, 0, 0, 0);
                    acc11 = __builtin_amdgcn_mfma_f32_32x32x16_bf16(a1_, b1_[kk], acc11, 0, 0, 0);
                }
            }
            __builtin_amdgcn_s_setprio(0);
        }
    }
#undef PPAIR

    // ---- epilogue: partial row-sum l, partial O ----
    lp += __shfl_xor(lp, 1);
    lp += __shfl_xor(lp, 2);
    if (pjq == 0) lpart[slice * NN + i0 + prow] = lp;

    float* obase = Opart + ((size_t)slice * NN + i0) * FOUT;
    // C/D 32x32: col = l31, row = (reg&3) + 8*(reg>>2) + 4*lq
#pragma unroll
    for (int rt = 0; rt < 2; rt++) {
#pragma unroll
        for (int nt = 0; nt < 2; nt++) {
            const float16v& av = rt == 0 ? (nt == 0 ? acc00 : acc01) : (nt == 0 ? acc10 : acc11);
#pragma unroll
            for (int reg = 0; reg < 16; reg++) {
                int row = rt * 32 + (reg & 3) + 8 * (reg >> 2) + 4 * lq;
                int n = wn0 + nt * 32 + l31;
                obase[(size_t)row * FOUT + n] = av[reg];
            }
        }
    }
}

// ---------------- Kernel 3: combine partials: out = sum_s O_s / sum_s l_s ----------------
__global__ __launch_bounds__(256) void combine_kernel(const float* __restrict__ Opart,
                                                      const float* __restrict__ lpart,
                                                      float* __restrict__ out, int slices) {
    int i = blockIdx.x, n = threadIdx.x;
    float o = 0.f, l = 0.f;
    for (int s = 0; s < slices; s++) {
        o += Opart[((size_t)s * NN + i) * FOUT + n];
        l += lpart[s * NN + i];
    }
    out[(size_t)i * FOUT + n] = o / l;
}

extern "C" void kernel_launch(void* const* d_in, const int* in_sizes, int n_in,
                              void* d_out, int out_size, void* d_ws, size_t ws_size,
                              hipStream_t stream) {
    const float* x   = (const float*)d_in[0];
    const int*   adj = (const int*)d_in[1];
    const float* W   = (const float*)d_in[2];
    const float* a   = (const float*)d_in[3];
    float* out = (float*)d_out;

    char* ws = (char*)d_ws;
    short* h_t   = (short*)ws;                                   // 4 MB
    short* Wt    = (short*)(ws + (4u << 20));                    // 256 KB
    float* f_src = (float*)(ws + (4u << 20) + (256u << 10));     // 32 KB
    float* f_dst = (float*)(ws + (4u << 20) + (288u << 10));     // 32 KB
    float* lpart = (float*)(ws + (4u << 20) + (320u << 10));     // up to 256 KB (8 slices)
    float* Opart = (float*)(ws + (5u << 20));                    // up to 64 MB

    const size_t OSLICE = (size_t)NN * FOUT * 4;                 // 8 MB per slice
    int slices = 1;
    if (ws_size >= (size_t)(5u << 20) + 6 * OSLICE) slices = 6;  // grid 768 = 3/CU exact
    else if (ws_size >= (size_t)(5u << 20) + 4 * OSLICE) slices = 4;
    else if (ws_size >= (size_t)(5u << 20) + 2 * OSLICE) slices = 2;
    const int NTILES = NN / 128;                                 // 64 tiles of 128 cols
    int qt = NTILES / slices, rt_ = NTILES % slices;

    hipMemsetAsync(f_src, 0, 2 * NN * sizeof(float), stream);
    wt_kernel<<<dim3(FIN / 32, FOUT / 32), 256, 0, stream>>>(W, Wt);
    h_kernel<<<512, 256, 0, stream>>>(x, Wt, a, h_t, f_src, f_dst);
    gat_kernel<<<dim3(NN / 64, slices), 256, 0, stream>>>(adj, h_t, f_src, f_dst,
                                                          Opart, lpart, qt, rt_);
    combine_kernel<<<NN, 256, 0, stream>>>(Opart, lpart, out, slices);
}